// Round 14
// baseline (54.423 us; speedup 1.0000x reference)
//
#include <hip/hip_runtime.h>

#define B_N 4096
#define M_N 3
#define D_N 256
#define LOG2E 1.44269504088896340736f
#define LN2   0.69314718055994530942f
#define C_OFF   64.0f
#define T_CLAMP 112.0f

typedef __bf16 bf16x8 __attribute__((ext_vector_type(8)));
typedef float  f32x4  __attribute__((ext_vector_type(4)));

__device__ __forceinline__ unsigned short f2bf(float f) {
    unsigned int u = __float_as_uint(f);
    u += 0x7FFFu + ((u >> 16) & 1u);   // round-to-nearest-even
    return (unsigned short)(u >> 16);
}
__device__ __forceinline__ float bf2f(unsigned short h) {
    return __uint_as_float(((unsigned int)h) << 16);
}

// tokens [i][m][d] f32 -> tokb [m][i][d] bf16; norm2[m*B+i] = sum(bf16(x)^2)
__global__ void cvt_kernel(const float* __restrict__ in, unsigned short* __restrict__ out,
                           float* __restrict__ norm2) {
    int idx = blockIdx.x * blockDim.x + threadIdx.x;   // 786432 float4s
    float4 v = reinterpret_cast<const float4*>(in)[idx];
    int i   = idx / 192;            // 192 = M*D/4
    int rem = idx - i * 192;
    int m   = rem >> 6;
    int d4  = rem & 63;
    ushort4 o;
    o.x = f2bf(v.x); o.y = f2bf(v.y); o.z = f2bf(v.z); o.w = f2bf(v.w);
    reinterpret_cast<ushort4*>(out)[((size_t)m * B_N + i) * 64 + d4] = o;
    float nx = bf2f(o.x), ny = bf2f(o.y), nz = bf2f(o.z), nw = bf2f(o.w);
    float s = nx * nx + ny * ny + nz * nz + nw * nw;
#pragma unroll
    for (int msk = 1; msk < 64; msk <<= 1) s += __shfl_xor(s, msk);
    if ((threadIdx.x & 63) == 0) norm2[m * B_N + i] = s;  // wave spans one (i,m) row
}

// Block: 64 rows x 512 cols of one modality; 2 WAVES x 32 rows (128 threads).
// Per-wave work per phase identical to the r4/r13 43.0 µs kernel; the change
// is barrier-group granularity: 6 blocks/CU = 6 independent 2-wave phase
// clocks per CU (vs 3 4-wave groups) to fill per-phase latency bubbles.
// Staging: 4 chunks/thread, LDS write linear in (q*2048 + tid*16) ->
// conflict-free; source pre-XOR'd per the verified involution.
// grid = 3m x 8ns x 64rb = 1536 blocks.
__global__ __launch_bounds__(128, 3) void main_kernel(
    const unsigned short* __restrict__ tokb, const int* __restrict__ labels,
    float2* __restrict__ partials) {
    int raw = blockIdx.x;
    int bid = (raw & 7) * 192 + (raw >> 3);  // bijective XCD swizzle (1536 % 8 == 0)
    int m  = bid >> 9;
    int ns = (bid >> 6) & 7;
    int rb = bid & 63;
    int i0 = rb * 64;
    int cb = ns * 512;

    int tid  = threadIdx.x;
    int wave = tid >> 6, lane = tid & 63;
    int lr = lane & 15, lk = lane >> 4;
    const unsigned short* tm = tokb + (size_t)m * (B_N * D_N);

    __shared__ __align__(16) char ldsB[2][8192];
    __shared__ int labl[512];
#pragma unroll
    for (int q = 0; q < 4; ++q) labl[q * 128 + tid] = labels[cb + q * 128 + tid];

    // A fragments: rows r0 + rt*16 + lr, registers for whole kernel
    int r0 = i0 + wave * 32;
    bf16x8 afrag[2][8];
#pragma unroll
    for (int rt = 0; rt < 2; ++rt) {
        const unsigned short* rp = tm + (size_t)(r0 + rt * 16 + lr) * D_N + lk * 8;
#pragma unroll
        for (int kf = 0; kf < 8; ++kf)
            afrag[rt][kf] = *reinterpret_cast<const bf16x8*>(rp + kf * 32);
    }
    int labr[2][4];
#pragma unroll
    for (int rt = 0; rt < 2; ++rt)
#pragma unroll
        for (int j = 0; j < 4; ++j)
            labr[rt][j] = labels[r0 + rt * 16 + lk * 4 + j];

    float S[2][4] = {{0.f, 0.f, 0.f, 0.f}, {0.f, 0.f, 0.f, 0.f}};
    float P[2][4] = {{0.f, 0.f, 0.f, 0.f}, {0.f, 0.f, 0.f, 0.f}};

    // Staging map (verified involution, rounds 4-13): LDS[col][ch] =
    // G[col][ch ^ (col&7)].  Thread t writes 4 chunks at q*2048 + t*16,
    // i.e. (col, ch) = (q*4 + (t>>5), t&31); source chunk = ch ^ (col&7).
    int lcq = tid >> 5;           // 0..3
    int ch  = tid & 31;
    const unsigned short* scol[4];
#pragma unroll
    for (int q = 0; q < 4; ++q) {
        int col = q * 4 + lcq;
        scol[q] = tm + (size_t)(cb + col) * D_N + (ch ^ (col & 7)) * 8;
    }

    // prologue: tile 0 -> buf 0
    {
#pragma unroll
        for (int q = 0; q < 4; ++q) {
            bf16x8 t0 = *reinterpret_cast<const bf16x8*>(scol[q]);
            *reinterpret_cast<bf16x8*>(&ldsB[0][q * 2048 + tid * 16]) = t0;
        }
    }

    for (int kb = 0; kb < 32; ++kb) {
        int cur = kb & 1;
        __syncthreads();   // buf[cur] staged; all reads of buf[cur^1] drained

        // issue next-tile global loads early (latency hides under compute)
        int nkb = (kb + 1) & 31;   // wrap: last-iter load/write is dead but safe
        size_t noff = (size_t)nkb * (16 * D_N);
        bf16x8 nt0 = *reinterpret_cast<const bf16x8*>(scol[0] + noff);
        bf16x8 nt1 = *reinterpret_cast<const bf16x8*>(scol[1] + noff);
        bf16x8 nt2 = *reinterpret_cast<const bf16x8*>(scol[2] + noff);
        bf16x8 nt3 = *reinterpret_cast<const bf16x8*>(scol[3] + noff);

        const char* bp = ldsB[cur];
        int swz = (lr & 7) << 4;
        bf16x8 bfrag[8];
#pragma unroll
        for (int kf = 0; kf < 8; ++kf)
            bfrag[kf] = *reinterpret_cast<const bf16x8*>(
                bp + lr * 512 + ((((kf * 4 + lk) << 4)) ^ swz));
        int labc = labl[kb * 16 + lr];

        f32x4 acc0 = {0.f, 0.f, 0.f, 0.f};
        f32x4 acc1 = {0.f, 0.f, 0.f, 0.f};
#pragma unroll
        for (int kf = 0; kf < 8; ++kf) {
            acc0 = __builtin_amdgcn_mfma_f32_16x16x32_bf16(afrag[0][kf], bfrag[kf], acc0, 0, 0, 0);
            acc1 = __builtin_amdgcn_mfma_f32_16x16x32_bf16(afrag[1][kf], bfrag[kf], acc1, 0, 0, 0);
        }

        int cg0 = cb + kb * 16;
        if ((cg0 < r0 + 32) && (cg0 + 16 > r0)) {
            int colg = cg0 + lr;
#pragma unroll
            for (int rt = 0; rt < 2; ++rt) {
                f32x4 aa = rt ? acc1 : acc0;
#pragma unroll
                for (int j = 0; j < 4; ++j) {
                    float s = aa[j];
                    float t = fminf(fmaf(s, LOG2E, -C_OFF), T_CLAMP);
                    float e = __builtin_amdgcn_exp2f(t);
                    int row = r0 + rt * 16 + lk * 4 + j;
                    e = (colg == row) ? 0.f : e;   // exclude self from partition
                    S[rt][j] += e;
                    P[rt][j] += (labc == labr[rt][j]) ? s : 0.f;  // diag in, -norm2 later
                }
            }
        } else {
#pragma unroll
            for (int rt = 0; rt < 2; ++rt) {
                f32x4 aa = rt ? acc1 : acc0;
#pragma unroll
                for (int j = 0; j < 4; ++j) {
                    float s = aa[j];
                    float t = fminf(fmaf(s, LOG2E, -C_OFF), T_CLAMP);
                    S[rt][j] += __builtin_amdgcn_exp2f(t);
                    P[rt][j] += (labc == labr[rt][j]) ? s : 0.f;
                }
            }
        }

        // write next tile (other buffer); barrier at loop top publishes it
        char* dst = (char*)ldsB[cur ^ 1];
        *reinterpret_cast<bf16x8*>(dst + tid * 16)        = nt0;
        *reinterpret_cast<bf16x8*>(dst + 2048 + tid * 16) = nt1;
        *reinterpret_cast<bf16x8*>(dst + 4096 + tid * 16) = nt2;
        *reinterpret_cast<bf16x8*>(dst + 6144 + tid * 16) = nt3;
    }

    // sum across the 16 col-lanes (lanes sharing lk hold the same rows)
#pragma unroll
    for (int rt = 0; rt < 2; ++rt)
#pragma unroll
        for (int j = 0; j < 4; ++j) {
            float sv = S[rt][j], pv = P[rt][j];
#pragma unroll
            for (int msk = 1; msk < 16; msk <<= 1) {
                sv += __shfl_xor(sv, msk);
                pv += __shfl_xor(pv, msk);
            }
            if (lr == 0) {
                int rl = rt * 16 + lk * 4 + j;
                float2 q; q.x = sv; q.y = pv;
                partials[(size_t)(((m * 64 + rb) * 8 + ns) * 64) + wave * 32 + rl] = q;
            }
        }
}

// one thread per (m,i): merge 8 col-split partials, finish the loss term.
// Histogram built in-block; block 0 publishes nv for final_kernel.
__global__ void reduce_kernel(const float2* __restrict__ partials,
                              const float* __restrict__ norm2,
                              const int* __restrict__ labels,
                              float* __restrict__ blockpart,
                              int* __restrict__ nvout) {
    __shared__ int h[32];
    int tid = threadIdx.x;
    if (tid < 32) h[tid] = 0;
    __syncthreads();
    for (int i = tid; i < B_N; i += 256) atomicAdd(&h[labels[i]], 1);
    __syncthreads();
    if (blockIdx.x == 0 && tid == 0) {
        int nv = 0;
#pragma unroll
        for (int c = 0; c < 32; ++c) nv += (h[c] >= 2) ? h[c] : 0;
        nvout[0] = nv;
    }
    int gid = blockIdx.x * 256 + tid;   // 12288
    int m = gid >> 12, i = gid & 4095;
    int rb = i >> 6, r = i & 63;
    const float2* pp = partials + (size_t)(((m * 64 + rb) * 8) * 64) + r;
    float S = 0.f, P = 0.f;
#pragma unroll
    for (int ns = 0; ns < 8; ++ns) {
        float2 q = pp[ns * 64];
        S += q.x; P += q.y;
    }
    P -= norm2[gid];                       // remove self-sim from positive sum
    int pc = h[labels[i]] - 1;
    float contrib = (pc > 0)
        ? (__builtin_amdgcn_logf(S) + C_OFF) * LN2 - P / (float)pc
        : 0.f;
#pragma unroll
    for (int off = 32; off >= 1; off >>= 1) contrib += __shfl_down(contrib, off);
    __shared__ float w4[4];
    if ((tid & 63) == 0) w4[tid >> 6] = contrib;
    __syncthreads();
    if (tid == 0) blockpart[blockIdx.x] = w4[0] + w4[1] + w4[2] + w4[3];
}

__global__ void final_kernel(const float* __restrict__ blockpart, const int* __restrict__ nv,
                             float* __restrict__ out) {
    int lane = threadIdx.x;
    float s = (lane < 48) ? blockpart[lane] : 0.f;
#pragma unroll
    for (int off = 32; off >= 1; off >>= 1) s += __shfl_down(s, off);
    if (lane == 0) out[0] = s / (float)(nv[0] * M_N);
}

extern "C" void kernel_launch(void* const* d_in, const int* in_sizes, int n_in,
                              void* d_out, int out_size, void* d_ws, size_t ws_size,
                              hipStream_t stream) {
    const float* tokens = (const float*)d_in[0];
    const int*   labels = (const int*)d_in[1];
    float* out = (float*)d_out;

    char* ws = (char*)d_ws;
    int*    nv        = (int*)(ws + 128);                   // 1 int
    float*  blockpart = (float*)(ws + 256);                 // 48 floats
    float*  norm2     = (float*)(ws + 1024);                // 12288 floats
    float2* partials  = (float2*)(ws + 65536);              // 98304 float2 = 786 KB
    unsigned short* tokb = (unsigned short*)(ws + 1048576); // 6.29 MB

    cvt_kernel<<<3072, 256, 0, stream>>>(tokens, tokb, norm2);
    main_kernel<<<1536, 128, 0, stream>>>(tokb, labels, partials);
    reduce_kernel<<<48, 256, 0, stream>>>(partials, norm2, labels, blockpart, nv);
    final_kernel<<<1, 64, 0, stream>>>(blockpart, nv, out);
}